// Round 3
// baseline (27.866 us; speedup 1.0000x reference)
//
#include <hip/hip_runtime.h>

// Multi-head embedding gather:
//   out[b,s,h,:] = weight[hash_ids[b,s,h] + offsets[h], :]
// B=4, S=4096, H=8, DIM=128 (fp32). Output rows = 131072.
// Memory-bound: each row is 512 B; 32 lanes x float4 = 512 B per row.
// Nontemporal hints (nt) on the streaming weight reads + output writes
// keep L2 free — neither stream has reuse. Native clang vector type is
// required for __builtin_nontemporal_* (HIP float4 is a struct).

typedef float f32x4 __attribute__((ext_vector_type(4)));

constexpr int DIM = 128;
constexpr int NHEADS = 8;
constexpr int LANES_PER_ROW = DIM / 4;  // 32 lanes, 16 B each

__global__ __launch_bounds__(256) void OffloadMultiHeadEmbedding_kernel(
    const int* __restrict__ hash_ids,   // [R] flattened (B*S*H), innermost = head
    const float* __restrict__ weight,   // [TOTAL, DIM]
    const int* __restrict__ offsets,    // [NHEADS]
    float* __restrict__ out,            // [R, DIM]
    int nrows)
{
    int t = blockIdx.x * blockDim.x + threadIdx.x;
    int row = t >> 5;          // 32 threads per output row
    int lane = t & 31;
    if (row >= nrows) return;

    int h = row & (NHEADS - 1);                 // head is the innermost index
    long gid = (long)hash_ids[row] + (long)offsets[h];

    const f32x4* src = reinterpret_cast<const f32x4*>(weight + (size_t)gid * DIM) + lane;
    f32x4*       dst = reinterpret_cast<f32x4*>(out + (size_t)row * DIM) + lane;

    f32x4 v = __builtin_nontemporal_load(src);
    __builtin_nontemporal_store(v, dst);
}

extern "C" void kernel_launch(void* const* d_in, const int* in_sizes, int n_in,
                              void* d_out, int out_size, void* d_ws, size_t ws_size,
                              hipStream_t stream) {
    const int*   hash_ids = (const int*)d_in[0];    // [B*S*H]
    const float* weight   = (const float*)d_in[1];  // [TOTAL, DIM]
    const int*   offsets  = (const int*)d_in[2];    // [NHEADS]
    float*       out      = (float*)d_out;

    int nrows = in_sizes[0];                        // 131072
    int total_threads = nrows * LANES_PER_ROW;
    int block = 256;
    int grid = (total_threads + block - 1) / block;

    OffloadMultiHeadEmbedding_kernel<<<grid, block, 0, stream>>>(
        hash_ids, weight, offsets, out, nrows);
}

// Round 4
// 25.328 us; speedup vs baseline: 1.1002x; 1.1002x over previous
//
#include <hip/hip_runtime.h>

// Multi-head embedding gather:
//   out[b,s,h,:] = weight[hash_ids[b,s,h] + offsets[h], :]
// B=4, S=4096, H=8, DIM=128 (fp32). Output rows = 131072.
// Memory-bound. 32 lanes x float4 = 512 B per row.
// Round-3 post-mortem: NT loads regressed (lost L2 dedup of ~8% repeated
// rows). This version: cached loads (keep dedup), NT stores only (output
// is write-once, never re-read -> keep it out of L2).

typedef float f32x4 __attribute__((ext_vector_type(4)));

constexpr int DIM = 128;
constexpr int NHEADS = 8;
constexpr int LANES_PER_ROW = DIM / 4;  // 32 lanes, 16 B each

__global__ __launch_bounds__(256) void OffloadMultiHeadEmbedding_kernel(
    const int* __restrict__ hash_ids,   // [R] flattened (B*S*H), innermost = head
    const float* __restrict__ weight,   // [TOTAL, DIM]
    const int* __restrict__ offsets,    // [NHEADS]
    float* __restrict__ out,            // [R, DIM]
    int nrows)
{
    int t = blockIdx.x * blockDim.x + threadIdx.x;
    int row = t >> 5;          // 32 threads per output row
    int lane = t & 31;
    if (row >= nrows) return;

    int h = row & (NHEADS - 1);                 // head is the innermost index
    long gid = (long)hash_ids[row] + (long)offsets[h];

    const f32x4* src = reinterpret_cast<const f32x4*>(weight + (size_t)gid * DIM) + lane;
    f32x4*       dst = reinterpret_cast<f32x4*>(out + (size_t)row * DIM) + lane;

    f32x4 v = *src;                       // cached: L2 dedups repeated rows
    __builtin_nontemporal_store(v, dst);  // streaming: don't pollute L2
}

extern "C" void kernel_launch(void* const* d_in, const int* in_sizes, int n_in,
                              void* d_out, int out_size, void* d_ws, size_t ws_size,
                              hipStream_t stream) {
    const int*   hash_ids = (const int*)d_in[0];    // [B*S*H]
    const float* weight   = (const float*)d_in[1];  // [TOTAL, DIM]
    const int*   offsets  = (const int*)d_in[2];    // [NHEADS]
    float*       out      = (float*)d_out;

    int nrows = in_sizes[0];                        // 131072
    int total_threads = nrows * LANES_PER_ROW;
    int block = 256;
    int grid = (total_threads + block - 1) / block;

    OffloadMultiHeadEmbedding_kernel<<<grid, block, 0, stream>>>(
        hash_ids, weight, offsets, out, nrows);
}